// Round 3
// baseline (163.354 us; speedup 1.0000x reference)
//
#include <hip/hip_runtime.h>

#define BATCH 16
#define HH    256
#define PITCH 84                       // floats; 84 % 32 == 20 -> uniform bank spread
#define ROWS  37                       // 32 tile rows + 5 halo (windows reach +6 from row 30)
#define PLSTRIDE (ROWS * PITCH)        // 3108 floats = 12432 B per plane (5*12432+2016+48 < 65536)
#define SMFLOATS (6 * PLSTRIDE)        // 18648 floats = 74592 B  -> 2 blocks/CU
#define NCHUNK 19                      // float4 chunks staged per row (76 floats)
#define STAGE_N (6 * ROWS * NCHUNK)    // 4218

__device__ __forceinline__ float elem4(const float4 v, int k) {
  return k == 0 ? v.x : k == 1 ? v.y : k == 2 ? v.z : v.w;
}

// window element IDX in [0,13]: 0..11 from W[pl][0..2], 12..13 from E[pl]
#define EL(PL, IDX)                                                          \
  ((IDX) < 12 ? elem4(W[PL][(((IDX) < 12 ? (IDX) : 0) >> 2)], (IDX)&3)       \
              : ((IDX) == 12 ? E[PL].x : E[PL].y))

// one pixel-pair: center row CR (A|B), strip col P, window element IDX.
// weight w = [center valid] + [target valid]  (0/1/2), applied via fma.
#define PAIRW(CR, P, IDX)                                                    \
  { float d0 = cen##CR[0][P] - EL(0, IDX);                                   \
    float d1 = cen##CR[1][P] - EL(1, IDX);                                   \
    float d2 = cen##CR[2][P] - EL(2, IDX);                                   \
    float d3 = cen##CR[3][P] - EL(3, IDX);                                   \
    float d4 = cen##CR[4][P] - EL(4, IDX);                                   \
    float d5 = cen##CR[5][P] - EL(5, IDX);                                   \
    float so = fabsf(d0) + fabsf(d1) + fabsf(d2);                            \
    float ss = fabsf(d3) + fabsf(d4) + fabsf(d5);                            \
    float w  = cenf##CR[P] + tk[IDX];                                        \
    acc[P] = fmaf(fabsf(so - ss), w, acc[P]); }

#define JROW(CR, J) PAIRW(CR, 0, (J)+5) PAIRW(CR, 1, (J)+6)                  \
                    PAIRW(CR, 2, (J)+7) PAIRW(CR, 3, (J)+8)
#define FULLROW(CR) JROW(CR,-5) JROW(CR,-4) JROW(CR,-3) JROW(CR,-2)          \
                    JROW(CR,-1) JROW(CR,0)  JROW(CR,1)  JROW(CR,2)           \
                    JROW(CR,3)  JROW(CR,4)  JROW(CR,5)

#define LOADW(BP)                                                            \
  { const float* bp_ = (BP);                                                 \
    _Pragma("unroll") for (int pl_ = 0; pl_ < 6; ++pl_) {                    \
      W[pl_][0] = *(const float4*)(bp_ + pl_ * PLSTRIDE);                    \
      W[pl_][1] = *(const float4*)(bp_ + pl_ * PLSTRIDE + 4);                \
      W[pl_][2] = *(const float4*)(bp_ + pl_ * PLSTRIDE + 8);                \
      E[pl_]    = *(const float2*)(bp_ + pl_ * PLSTRIDE + 12);               \
    } }

// target row for ANY use of window row K is pyA+K (shared by strip rows A,B)
#define TKCALC(K)                                                            \
  { float yk_ = ((unsigned)(pyA + (K)) < 246u) ? 1.0f : 0.0f;                \
    _Pragma("unroll") for (int ii_ = 0; ii_ < 14; ++ii_)                     \
      tk[ii_] = yk_ * xokf[ii_]; }

#define CENEXT(CR)                                                           \
  { _Pragma("unroll") for (int pl_ = 0; pl_ < 6; ++pl_) {                    \
      cen##CR[pl_][0] = W[pl_][1].y; cen##CR[pl_][1] = W[pl_][1].z;          \
      cen##CR[pl_][2] = W[pl_][1].w; cen##CR[pl_][3] = W[pl_][2].x; } }

__global__ __launch_bounds__(256, 2)
void contrast_loss_kernel(const float* __restrict__ orig,
                          const float* __restrict__ sim,
                          float* __restrict__ out) {
  __shared__ float sm[SMFLOATS];
  __shared__ float wsum[4];

  const int tid = threadIdx.x;
  const int bx = blockIdx.x, by = blockIdx.y, b = blockIdx.z;
  const int cbase = bx * 64 - 5;   // image col of LDS col 0
  const int rbase = by * 32;       // image row of LDS row 0

  const float* img0 = orig + (size_t)b * 3 * HH * HH;
  const float* img1 = sim  + (size_t)b * 3 * HH * HH;

  // ---- staging: 6 planes x 37 rows x 76 cols, float4, clamped at edges ----
  for (int t = tid; t < STAGE_N; t += 256) {
    const int pl  = t / (ROWS * NCHUNK);
    const int rem = t - pl * (ROWS * NCHUNK);
    const int r   = rem / NCHUNK;
    const int c4  = rem - r * NCHUNK;
    int row = rbase + r; row = row < HH ? row : HH - 1;
    const float* src = (pl >= 3 ? img1 + (pl - 3) * (HH * HH)
                                : img0 + pl * (HH * HH)) + (size_t)row * HH;
    const int col0 = cbase + 4 * c4;
    float4 v;
    if ((unsigned)col0 <= (unsigned)(HH - 4)) {
      v = *(const float4*)(src + col0);
    } else {
      int c0 = col0 + 0; c0 = c0 < 0 ? 0 : (c0 < HH ? c0 : HH - 1);
      int c1 = col0 + 1; c1 = c1 < 0 ? 0 : (c1 < HH ? c1 : HH - 1);
      int c2 = col0 + 2; c2 = c2 < 0 ? 0 : (c2 < HH ? c2 : HH - 1);
      int c3 = col0 + 3; c3 = c3 < 0 ? 0 : (c3 < HH ? c3 : HH - 1);
      v.x = src[c0]; v.y = src[c1]; v.z = src[c2]; v.w = src[c3];
    }
    *(float4*)&sm[pl * PLSTRIDE + r * PITCH + 4 * c4] = v;
  }
  __syncthreads();

  // ---- geometry: wave = 8 x-strips (32 cols) x 8 y-strips (16 rows) ----
  const int lane = tid & 63;
  const int wv   = tid >> 6;
  const int lx = lane & 7, ly = lane >> 3;
  const int xh = wv & 1,  yh = wv >> 1;
  const int xi  = xh * 32 + lx * 4;     // LDS col of window start
  const int yiA = yh * 16 + ly * 2;     // LDS row of strip row A center
  const int xp0 = cbase + xi;           // p'_x for p=0
  const int pyA = rbase + yiA - 5;      // p'_y of row A

  // validity factors (1.0 interior, 0.0 outside [0,245])
  float xokf[14];
  #pragma unroll
  for (int idx = 0; idx < 14; ++idx)
    xokf[idx] = ((unsigned)(xp0 + idx - 5) < 246u) ? 1.0f : 0.0f;
  const float cyA = ((unsigned)pyA < 246u) ? 1.0f : 0.0f;
  const float cyB = ((unsigned)(pyA + 1) < 246u) ? 1.0f : 0.0f;
  float cenfA[4], cenfB[4];
  #pragma unroll
  for (int p = 0; p < 4; ++p) {
    cenfA[p] = cyA * xokf[p + 5];
    cenfB[p] = cyB * xokf[p + 5];
  }

  float4 W[6][3]; float2 E[6];
  float cenA[6][4], cenB[6][4];
  float tk[14];
  float acc[4] = {0.f, 0.f, 0.f, 0.f};

  const float* base = &sm[yiA * PITCH + xi];

  // k = 0: extract cenA; row A shift i=0, j=1..5
  LOADW(base);
  CENEXT(A)
  TKCALC(0)
  JROW(A, 1) JROW(A, 2) JROW(A, 3) JROW(A, 4) JROW(A, 5)

  // k = 1: extract cenB; row A i=1 full; row B i=0, j=1..5
  base += PITCH;
  LOADW(base);
  CENEXT(B)
  TKCALC(1)
  FULLROW(A)
  JROW(B, 1) JROW(B, 2) JROW(B, 3) JROW(B, 4) JROW(B, 5)

  // k = 2..5: row A i=k full; row B i=k-1 full  (rolled: keeps I-cache small)
  #pragma unroll 1
  for (int k = 2; k <= 5; ++k) {
    base += PITCH;
    LOADW(base);
    TKCALC(k)
    FULLROW(A)
    FULLROW(B)
  }

  // k = 6: row B i=5 full
  base += PITCH;
  LOADW(base);
  TKCALC(6)
  FULLROW(B)

  // ---- reduce: wave shuffle -> LDS -> one atomic per block ----
  float tot = acc[0] + acc[1] + acc[2] + acc[3];
  #pragma unroll
  for (int off = 32; off > 0; off >>= 1)
    tot += __shfl_down(tot, off, 64);
  if (lane == 0) wsum[wv] = tot;
  __syncthreads();
  if (tid == 0) {
    const float scale = 1.0f / 116190720.0f;   // 16*246*246*120
    atomicAdd(out, (wsum[0] + wsum[1] + wsum[2] + wsum[3]) * scale);
  }
}

extern "C" void kernel_launch(void* const* d_in, const int* in_sizes, int n_in,
                              void* d_out, int out_size, void* d_ws, size_t ws_size,
                              hipStream_t stream) {
  (void)in_sizes; (void)n_in; (void)d_ws; (void)ws_size; (void)out_size;
  const float* orig = (const float*)d_in[0];
  const float* sim  = (const float*)d_in[1];
  float* out = (float*)d_out;

  hipMemsetAsync(out, 0, sizeof(float), stream);

  dim3 grid(4, 8, BATCH);   // 512 blocks = exactly 2 resident per CU
  dim3 block(256);
  hipLaunchKernelGGL(contrast_loss_kernel, grid, block, 0, stream, orig, sim, out);
}

// Round 4
// 126.044 us; speedup vs baseline: 1.2960x; 1.2960x over previous
//
#include <hip/hip_runtime.h>

#define BATCH 16
#define HH    256
#define PITCH 76                     // floats; with 8x8 lane geometry start-quads uniform
#define ROWS  21                     // 16 tile rows + 5 halo
#define PLSTRIDE (ROWS * PITCH)      // 1596 floats = 6384 B per plane
#define SMFLOATS (6 * PLSTRIDE)      // 9576 floats = 38304 B -> 4 blocks/CU
#define NCHUNK 19                    // float4 chunks per row (76 floats exactly)
#define STAGE_N (6 * ROWS * NCHUNK)  // 2394

__device__ __forceinline__ float elem4(const float4 v, int k) {
  return k == 0 ? v.x : k == 1 ? v.y : k == 2 ? v.z : v.w;
}

// Window element IDX in [0,13]: 0..11 from W[pl][0..2], 12..13 from E[pl].
#define EL(PL, IDX)                                                         \
  ((IDX) < 12 ? elem4(W[(PL)][(((IDX) < 12 ? (IDX) : 0) >> 2)], (IDX)&3)    \
              : ((IDX) == 12 ? E[(PL)].x : E[(PL)].y))

#define DIFF6(P, IDX, FV)                                                   \
  float FV;                                                                 \
  {                                                                         \
    float so_ = fabsf(cen[0][(P)] - EL(0, IDX))                             \
              + fabsf(cen[1][(P)] - EL(1, IDX))                             \
              + fabsf(cen[2][(P)] - EL(2, IDX));                            \
    float ss_ = fabsf(cen[3][(P)] - EL(3, IDX))                             \
              + fabsf(cen[4][(P)] - EL(4, IDX))                             \
              + fabsf(cen[5][(P)] - EL(5, IDX));                            \
    FV = fabsf(so_ - ss_);                                                  \
  }

// fast: weight 2 applied at the end
#define SF(P, J) { DIFF6(P, (P) + (J) + 5, f_) accV[(P)] += f_; }
// masked: accV masked by m0 at end; accS masked per-shift by target validity
#define SMK(P, J)                                                           \
  { DIFF6(P, (P) + (J) + 5, f_) accV[(P)] += f_;                            \
    accS[(P)] += (yok && ((unsigned)(xp[(P)] + (J)) < 246u)) ? f_ : 0.0f; }

#define JF(J) SF(0, J) SF(1, J) SF(2, J) SF(3, J)
#define JM(J) SMK(0, J) SMK(1, J) SMK(2, J) SMK(3, J)

// all reads at compile-time offsets from one base pointer (max 33776 B < 64K)
#define LOADW(ROWOFF)                                                       \
  { _Pragma("unroll") for (int pl_ = 0; pl_ < 6; ++pl_) {                   \
      W[pl_][0] = *(const float4*)(base + pl_ * PLSTRIDE + (ROWOFF));       \
      W[pl_][1] = *(const float4*)(base + pl_ * PLSTRIDE + (ROWOFF) + 4);   \
      W[pl_][2] = *(const float4*)(base + pl_ * PLSTRIDE + (ROWOFF) + 8);   \
      E[pl_]    = *(const float2*)(base + pl_ * PLSTRIDE + (ROWOFF) + 12);  \
    } }

__global__ __launch_bounds__(256, 4)
void contrast_loss_kernel(const float* __restrict__ orig,
                          const float* __restrict__ sim,
                          float* __restrict__ out) {
  __shared__ float sm[SMFLOATS];
  __shared__ float wsum[4];

  const int tid = threadIdx.x;
  const int bx = blockIdx.x, by = blockIdx.y, b = blockIdx.z;
  const int cbase = bx * 64 - 5;  // image col of LDS col 0 (also p'x of col 0)
  const int rbase = by * 16;      // image row of LDS row 0

  const float* img0 = orig + (size_t)b * 3 * HH * HH;
  const float* img1 = sim  + (size_t)b * 3 * HH * HH;

  // ---- staging: 6 planes x 21 rows x 76 cols, float4, clamped at edges ----
  for (int t = tid; t < STAGE_N; t += 256) {
    const int pl  = t / (ROWS * NCHUNK);
    const int rem = t - pl * (ROWS * NCHUNK);
    const int r   = rem / NCHUNK;
    const int c4  = rem - r * NCHUNK;
    int row = rbase + r; row = row < HH ? row : HH - 1;
    const float* src = (pl >= 3 ? img1 + (pl - 3) * (HH * HH)
                                : img0 + pl * (HH * HH)) + (size_t)row * HH;
    const int col0 = cbase + 4 * c4;
    float4 v;
    if ((unsigned)col0 <= (unsigned)(HH - 4)) {
      v = *(const float4*)(src + col0);
    } else {
      int c0 = col0 + 0; c0 = c0 < 0 ? 0 : (c0 < HH ? c0 : HH - 1);
      int c1 = col0 + 1; c1 = c1 < 0 ? 0 : (c1 < HH ? c1 : HH - 1);
      int c2 = col0 + 2; c2 = c2 < 0 ? 0 : (c2 < HH ? c2 : HH - 1);
      int c3 = col0 + 3; c3 = c3 < 0 ? 0 : (c3 < HH ? c3 : HH - 1);
      v.x = src[c0]; v.y = src[c1]; v.z = src[c2]; v.w = src[c3];
    }
    *(float4*)&sm[pl * PLSTRIDE + r * PITCH + 4 * c4] = v;
  }
  __syncthreads();

  // ---- thread geometry: wave footprint = 32 cols x 8 rows ----
  const int lane  = tid & 63;
  const int wave  = tid >> 6;
  const int xhalf = wave & 1;
  const int ywave = wave >> 1;
  const int lx = lane & 7, ly = lane >> 3;
  const int xi = xhalf * 32 + lx * 4;   // LDS col of window start
  const int yi = ywave * 8 + ly;        // LDS row of center row

  const int y   = rbase + yi - 5;   // p'_y
  const int xp0 = cbase + xi;       // p'_x for p=0

  float4 W[6][3];
  float2 E[6];
  float  cen[6][4];
  float  accV[4] = {0.f, 0.f, 0.f, 0.f};
  float  accS[4] = {0.f, 0.f, 0.f, 0.f};

  const float* base = &sm[yi * PITCH + xi];

  // wave-uniform interior test: all lanes weight-2 for all 60 shifts
  const int wx_lo = cbase + xhalf * 32;
  const int wy_lo = rbase - 5 + ywave * 8;
  const bool fastw = (wx_lo >= 5) && (wx_lo + 31 <= 240) &&
                     (wy_lo >= 0) && (wy_lo + 7 <= 240);

  // i = 0 window (center row)
  LOADW(0)
  #pragma unroll
  for (int pl = 0; pl < 6; ++pl) {     // center = window idx p+5
    cen[pl][0] = W[pl][1].y;
    cen[pl][1] = W[pl][1].z;
    cen[pl][2] = W[pl][1].w;
    cen[pl][3] = W[pl][2].x;
  }

  float tot;
  if (fastw) {
    JF(1) JF(2) JF(3) JF(4) JF(5)                 // i=0: j=1..5
    LOADW(1 * PITCH)
    JF(-5) JF(-4) JF(-3) JF(-2) JF(-1) JF(0) JF(1) JF(2) JF(3) JF(4) JF(5)
    LOADW(2 * PITCH)
    JF(-5) JF(-4) JF(-3) JF(-2) JF(-1) JF(0) JF(1) JF(2) JF(3) JF(4) JF(5)
    LOADW(3 * PITCH)
    JF(-5) JF(-4) JF(-3) JF(-2) JF(-1) JF(0) JF(1) JF(2) JF(3) JF(4) JF(5)
    LOADW(4 * PITCH)
    JF(-5) JF(-4) JF(-3) JF(-2) JF(-1) JF(0) JF(1) JF(2) JF(3) JF(4) JF(5)
    LOADW(5 * PITCH)
    JF(-5) JF(-4) JF(-3) JF(-2) JF(-1) JF(0) JF(1) JF(2) JF(3) JF(4) JF(5)
    tot = 2.0f * (accV[0] + accV[1] + accV[2] + accV[3]);
  } else {
    const int xp[4] = {xp0, xp0 + 1, xp0 + 2, xp0 + 3};
    bool yok = ((unsigned)y < 246u);              // i = 0
    JM(1) JM(2) JM(3) JM(4) JM(5)
    #pragma unroll 1
    for (int ii = 1; ii <= 5; ++ii) {
      base += PITCH;
      LOADW(0)
      yok = ((unsigned)(y + ii) < 246u);
      JM(-5) JM(-4) JM(-3) JM(-2) JM(-1) JM(0) JM(1) JM(2) JM(3) JM(4) JM(5)
    }
    tot = 0.f;
    const bool ym0 = ((unsigned)y < 246u);
    #pragma unroll
    for (int p = 0; p < 4; ++p) {
      const bool m0 = ym0 && ((unsigned)xp[p] < 246u);
      tot += (m0 ? accV[p] : 0.f) + accS[p];
    }
  }

  // ---- reduce: wave shuffle -> LDS -> one atomic per block ----
  #pragma unroll
  for (int off = 32; off > 0; off >>= 1)
    tot += __shfl_down(tot, off, 64);
  if (lane == 0) wsum[wave] = tot;
  __syncthreads();
  if (tid == 0) {
    const float scale = 1.0f / 116190720.0f;   // 16*246*246*120
    atomicAdd(out, (wsum[0] + wsum[1] + wsum[2] + wsum[3]) * scale);
  }
}

extern "C" void kernel_launch(void* const* d_in, const int* in_sizes, int n_in,
                              void* d_out, int out_size, void* d_ws, size_t ws_size,
                              hipStream_t stream) {
  (void)in_sizes; (void)n_in; (void)d_ws; (void)ws_size; (void)out_size;
  const float* orig = (const float*)d_in[0];
  const float* sim  = (const float*)d_in[1];
  float* out = (float*)d_out;

  hipMemsetAsync(out, 0, sizeof(float), stream);

  dim3 grid(4, 16, BATCH);   // 1024 blocks = exactly 4 resident per CU, one generation
  dim3 block(256);
  hipLaunchKernelGGL(contrast_loss_kernel, grid, block, 0, stream, orig, sim, out);
}

// Round 5
// 109.857 us; speedup vs baseline: 1.4870x; 1.1474x over previous
//
#include <hip/hip_runtime.h>

#define BATCH 16
#define HH    256
#define PITCH 76                     // floats; 8x8 lane geometry -> perfectly uniform banks
#define ROWS  21                     // 16 tile rows + 5 halo
#define PLSTRIDE (ROWS * PITCH)      // 1596 floats = 6384 B per plane
#define SMFLOATS (6 * PLSTRIDE)      // 9576 floats = 38304 B -> 4 blocks/CU
#define NCHUNK 19                    // float4 chunks per row (76 floats exactly)
#define STAGE_N (6 * ROWS * NCHUNK)  // 2394

__device__ __forceinline__ float elem4(const float4 v, int k) {
  return k == 0 ? v.x : k == 1 ? v.y : k == 2 ? v.z : v.w;
}

// Window element IDX in [0,13]: 0..11 from W[pl][0..2], 12..13 from E[pl].
#define EL(PL, IDX)                                                         \
  ((IDX) < 12 ? elem4(W[(PL)][(((IDX) < 12 ? (IDX) : 0) >> 2)], (IDX)&3)    \
              : ((IDX) == 12 ? E[(PL)].x : E[(PL)].y))

#define DIFF6(P, IDX, FV)                                                   \
  float FV;                                                                 \
  {                                                                         \
    float so_ = fabsf(cen[0][(P)] - EL(0, IDX))                             \
              + fabsf(cen[1][(P)] - EL(1, IDX))                             \
              + fabsf(cen[2][(P)] - EL(2, IDX));                            \
    float ss_ = fabsf(cen[3][(P)] - EL(3, IDX))                             \
              + fabsf(cen[4][(P)] - EL(4, IDX))                             \
              + fabsf(cen[5][(P)] - EL(5, IDX));                            \
    FV = fabsf(so_ - ss_);                                                  \
  }

// fast: weight 2 applied at the end
#define SF(P, J) { DIFF6(P, (P) + (J) + 5, f_) accV[(P)] += f_; }
// masked: accV masked by m0 at end; accS masked per-shift by target validity
#define SMK(P, J)                                                           \
  { DIFF6(P, (P) + (J) + 5, f_) accV[(P)] += f_;                            \
    accS[(P)] += (yok && ((unsigned)(xp[(P)] + (J)) < 246u)) ? f_ : 0.0f; }

#define JF(J) SF(0, J) SF(1, J) SF(2, J) SF(3, J)
#define JM(J) SMK(0, J) SMK(1, J) SMK(2, J) SMK(3, J)

#define LOADW(BP)                                                           \
  { const float* bp_ = (BP);                                                \
    _Pragma("unroll") for (int pl_ = 0; pl_ < 6; ++pl_) {                   \
      W[pl_][0] = *(const float4*)(bp_ + pl_ * PLSTRIDE);                   \
      W[pl_][1] = *(const float4*)(bp_ + pl_ * PLSTRIDE + 4);               \
      W[pl_][2] = *(const float4*)(bp_ + pl_ * PLSTRIDE + 8);               \
      E[pl_]    = *(const float2*)(bp_ + pl_ * PLSTRIDE + 12);              \
    } }

__global__ __launch_bounds__(256, 2)
void contrast_loss_kernel(const float* __restrict__ orig,
                          const float* __restrict__ sim,
                          float* __restrict__ out) {
  __shared__ float sm[SMFLOATS];
  __shared__ float wsum[4];

  const int tid = threadIdx.x;
  const int bx = blockIdx.x, by = blockIdx.y, b = blockIdx.z;
  const int cbase = bx * 64 - 5;  // image col of LDS col 0 (also p'x of col 0)
  const int rbase = by * 16;      // image row of LDS row 0

  const float* img0 = orig + (size_t)b * 3 * HH * HH;
  const float* img1 = sim  + (size_t)b * 3 * HH * HH;

  // ---- staging: 6 planes x 21 rows x 76 cols, float4, clamped at edges ----
  for (int t = tid; t < STAGE_N; t += 256) {
    const int pl  = t / (ROWS * NCHUNK);
    const int rem = t - pl * (ROWS * NCHUNK);
    const int r   = rem / NCHUNK;
    const int c4  = rem - r * NCHUNK;
    int row = rbase + r; row = row < HH ? row : HH - 1;
    const float* src = (pl >= 3 ? img1 + (pl - 3) * (HH * HH)
                                : img0 + pl * (HH * HH)) + (size_t)row * HH;
    const int col0 = cbase + 4 * c4;
    float4 v;
    if ((unsigned)col0 <= (unsigned)(HH - 4)) {
      v = *(const float4*)(src + col0);
    } else {
      int c0 = col0 + 0; c0 = c0 < 0 ? 0 : (c0 < HH ? c0 : HH - 1);
      int c1 = col0 + 1; c1 = c1 < 0 ? 0 : (c1 < HH ? c1 : HH - 1);
      int c2 = col0 + 2; c2 = c2 < 0 ? 0 : (c2 < HH ? c2 : HH - 1);
      int c3 = col0 + 3; c3 = c3 < 0 ? 0 : (c3 < HH ? c3 : HH - 1);
      v.x = src[c0]; v.y = src[c1]; v.z = src[c2]; v.w = src[c3];
    }
    *(float4*)&sm[pl * PLSTRIDE + r * PITCH + 4 * c4] = v;
  }
  __syncthreads();

  // ---- thread geometry: wave footprint = 32 cols x 8 rows ----
  const int lane  = tid & 63;
  const int wave  = tid >> 6;
  const int xhalf = wave & 1;
  const int ywave = wave >> 1;
  const int lx = lane & 7, ly = lane >> 3;
  const int xi = xhalf * 32 + lx * 4;   // LDS col of window start
  const int yi = ywave * 8 + ly;        // LDS row of center row

  const int y   = rbase + yi - 5;   // p'_y
  const int xp0 = cbase + xi;       // p'_x for p=0

  float4 W[6][3];
  float2 E[6];
  float  cen[6][4];
  float  accV[4] = {0.f, 0.f, 0.f, 0.f};
  float  accS[4] = {0.f, 0.f, 0.f, 0.f};

  const float* base = &sm[yi * PITCH + xi];

  // wave-uniform interior test: all lanes weight-2 for all 60 shifts
  const int wx_lo = cbase + xhalf * 32;
  const int wy_lo = rbase - 5 + ywave * 8;
  const bool fastw = (wx_lo >= 5) && (wx_lo + 31 <= 240) &&
                     (wy_lo >= 0) && (wy_lo + 7 <= 240);

  // i = 0 window (center row)
  LOADW(base);
  #pragma unroll
  for (int pl = 0; pl < 6; ++pl) {     // center = window idx p+5
    cen[pl][0] = W[pl][1].y;
    cen[pl][1] = W[pl][1].z;
    cen[pl][2] = W[pl][1].w;
    cen[pl][3] = W[pl][2].x;
  }

  float tot;
  if (fastw) {
    // i = 0: j = 1..5
    JF(1) JF(2) JF(3) JF(4) JF(5)
    #pragma unroll 1
    for (int ii = 1; ii <= 5; ++ii) {
      base += PITCH;
      LOADW(base);
      JF(-5) JF(-4) JF(-3) JF(-2) JF(-1) JF(0) JF(1) JF(2) JF(3) JF(4) JF(5)
    }
    tot = 2.0f * (accV[0] + accV[1] + accV[2] + accV[3]);
  } else {
    const int xp[4] = {xp0, xp0 + 1, xp0 + 2, xp0 + 3};
    bool yok = ((unsigned)y < 246u);            // i = 0
    JM(1) JM(2) JM(3) JM(4) JM(5)
    #pragma unroll 1
    for (int ii = 1; ii <= 5; ++ii) {
      base += PITCH;
      LOADW(base);
      yok = ((unsigned)(y + ii) < 246u);
      JM(-5) JM(-4) JM(-3) JM(-2) JM(-1) JM(0) JM(1) JM(2) JM(3) JM(4) JM(5)
    }
    tot = 0.f;
    const bool ym0 = ((unsigned)y < 246u);
    #pragma unroll
    for (int p = 0; p < 4; ++p) {
      const bool m0 = ym0 && ((unsigned)xp[p] < 246u);
      tot += (m0 ? accV[p] : 0.f) + accS[p];
    }
  }

  // ---- reduce: wave shuffle -> LDS -> one atomic per block ----
  #pragma unroll
  for (int off = 32; off > 0; off >>= 1)
    tot += __shfl_down(tot, off, 64);
  if (lane == 0) wsum[wave] = tot;
  __syncthreads();
  if (tid == 0) {
    const float scale = 1.0f / 116190720.0f;   // 16*246*246*120
    atomicAdd(out, (wsum[0] + wsum[1] + wsum[2] + wsum[3]) * scale);
  }
}

extern "C" void kernel_launch(void* const* d_in, const int* in_sizes, int n_in,
                              void* d_out, int out_size, void* d_ws, size_t ws_size,
                              hipStream_t stream) {
  (void)in_sizes; (void)n_in; (void)d_ws; (void)ws_size; (void)out_size;
  const float* orig = (const float*)d_in[0];
  const float* sim  = (const float*)d_in[1];
  float* out = (float*)d_out;

  hipMemsetAsync(out, 0, sizeof(float), stream);

  dim3 grid(4, 16, BATCH);   // 1024 blocks = exactly 4 resident per CU, one generation
  dim3 block(256);
  hipLaunchKernelGGL(contrast_loss_kernel, grid, block, 0, stream, orig, sim, out);
}

// Round 6
// 102.131 us; speedup vs baseline: 1.5995x; 1.0756x over previous
//
#include <hip/hip_runtime.h>

#define BATCH 16
#define HH    256
#define ROWH  80                       // halves per LDS row (160 B)
#define ROWS  21                       // 16 tile rows + 5 halo
#define PLH   (ROWS * ROWH)            // 1680 halves per plane (3360 B)
#define SMH   (6 * PLH)                // 10080 halves = 20160 B -> 8 blocks/CU by LDS
#define NCH   20                       // 4-half chunks per row

typedef _Float16 half_t;
typedef _Float16 h2 __attribute__((ext_vector_type(2)));

__device__ __forceinline__ h2 H2(unsigned u) { return __builtin_bit_cast(h2, u); }
__device__ __forceinline__ unsigned U32(h2 x) { return __builtin_bit_cast(unsigned, x); }
__device__ __forceinline__ h2 absh(h2 x) { return H2(U32(x) & 0x7FFF7FFFu); }

// packed pair of window halves (M, M+1); M compile-time, wd = 8 dwords (16 halves)
template<int M>
__device__ __forceinline__ h2 exth(const unsigned* wd) {
  if constexpr ((M & 1) == 0) return H2(wd[M / 2]);
  else return H2((wd[(M - 1) / 2] >> 16) | (wd[(M + 1) / 2] << 16));   // alignbit
}

// |so - ss| for 2 outputs at window-half start M
template<int M>
__device__ __forceinline__ h2 term(const unsigned (&wd)[6][8], const h2 (&cen)[6]) {
  h2 d0 = cen[0] - exth<M>(wd[0]);
  h2 d1 = cen[1] - exth<M>(wd[1]);
  h2 d2 = cen[2] - exth<M>(wd[2]);
  h2 d3 = cen[3] - exth<M>(wd[3]);
  h2 d4 = cen[4] - exth<M>(wd[4]);
  h2 d5 = cen[5] - exth<M>(wd[5]);
  h2 so = absh(d0) + absh(d1) + absh(d2);
  h2 ss = absh(d3) + absh(d4) + absh(d5);
  return absh(so - ss);
}

// fast (interior wave): unit weight now, x2 at the end
#define SHF(IDX) { accA += term<IDX>(wd, cenA); accB += term<(IDX)+2>(wd, cenB); }
// masked: weight = center-valid + yok * target-valid, all exact {0,1,2} in fp16
#define SHM(IDX) { accA += term<IDX>(wd, cenA) * (cenfA + yok2 * exth<IDX>(xk));        \
                   accB += term<(IDX)+2>(wd, cenB) * (cenfB + yok2 * exth<(IDX)+2>(xk)); }

#define ROWF SHF(0) SHF(1) SHF(2) SHF(3) SHF(4) SHF(5) SHF(6) SHF(7) SHF(8) SHF(9) SHF(10)
#define ROWM SHM(0) SHM(1) SHM(2) SHM(3) SHM(4) SHM(5) SHM(6) SHM(7) SHM(8) SHM(9) SHM(10)

#define LOADROW(RP)                                                          \
  { _Pragma("unroll") for (int pl_ = 0; pl_ < 6; ++pl_) {                    \
      const _Float16* q_ = (RP) + pl_ * PLH;                                 \
      uint2 a_ = *(const uint2*)(q_);                                        \
      uint2 b_ = *(const uint2*)(q_ + 4);                                    \
      uint2 c_ = *(const uint2*)(q_ + 8);                                    \
      uint2 d_ = *(const uint2*)(q_ + 12);                                   \
      wd[pl_][0] = a_.x; wd[pl_][1] = a_.y; wd[pl_][2] = b_.x;               \
      wd[pl_][3] = b_.y; wd[pl_][4] = c_.x; wd[pl_][5] = c_.y;               \
      wd[pl_][6] = d_.x; wd[pl_][7] = d_.y; } }

__global__ __launch_bounds__(256, 2)
void contrast_loss_kernel(const float* __restrict__ orig,
                          const float* __restrict__ sim,
                          float* __restrict__ out) {
  __shared__ _Float16 sm[SMH];
  __shared__ float wsum[4];

  const int tid = threadIdx.x;
  const int bx = blockIdx.x, by = blockIdx.y, b = blockIdx.z;
  const int cbase = bx * 64 - 5;   // image col of LDS col 0 (= p'x of col 0)
  const int rbase = by * 16;       // image row of LDS row 0

  const float* img0 = orig + (size_t)b * 3 * HH * HH;
  const float* img1 = sim  + (size_t)b * 3 * HH * HH;

  // ---- staging: 6 planes x 21 rows x 80 halves; fp32->fp16 RNE; clamped ----
  for (int t = tid; t < 6 * ROWS * NCH; t += 256) {
    const int pl  = t / (ROWS * NCH);
    const int rem = t - pl * (ROWS * NCH);
    const int r   = rem / NCH;
    const int c4  = rem - r * NCH;
    int row = rbase + r; row = row < HH ? row : HH - 1;
    const float* src = (pl >= 3 ? img1 + (pl - 3) * (HH * HH)
                                : img0 + pl * (HH * HH)) + (size_t)row * HH;
    const int col0 = cbase + 4 * c4;
    float4 v;
    if ((unsigned)col0 <= (unsigned)(HH - 4)) {
      v = *(const float4*)(src + col0);
    } else {
      int c0 = col0 + 0; c0 = c0 < 0 ? 0 : (c0 < HH ? c0 : HH - 1);
      int c1 = col0 + 1; c1 = c1 < 0 ? 0 : (c1 < HH ? c1 : HH - 1);
      int c2 = col0 + 2; c2 = c2 < 0 ? 0 : (c2 < HH ? c2 : HH - 1);
      int c3 = col0 + 3; c3 = c3 < 0 ? 0 : (c3 < HH ? c3 : HH - 1);
      v.x = src[c0]; v.y = src[c1]; v.z = src[c2]; v.w = src[c3];
    }
    h2 lo, hi;
    lo.x = (half_t)v.x; lo.y = (half_t)v.y;
    hi.x = (half_t)v.z; hi.y = (half_t)v.w;
    uint2 pk; pk.x = U32(lo); pk.y = U32(hi);
    *(uint2*)&sm[pl * PLH + r * ROWH + 4 * c4] = pk;
  }
  __syncthreads();

  // ---- geometry: wave footprint = 32 cols x 8 rows (as r5, verified) ----
  const int lane  = tid & 63;
  const int wave  = tid >> 6;
  const int xhalf = wave & 1;
  const int ywave = wave >> 1;
  const int lx = lane & 7, ly = lane >> 3;
  const int xi = xhalf * 32 + lx * 4;   // LDS half-col of window start
  const int yi = ywave * 8 + ly;        // LDS row of center row

  const int y   = rbase + yi - 5;   // p'_y
  const int xp0 = cbase + xi;       // p'_x for p=0

  unsigned wd[6][8];
  h2 cenA[6], cenB[6];
  h2 accA = {(half_t)0.0f, (half_t)0.0f};
  h2 accB = {(half_t)0.0f, (half_t)0.0f};

  const _Float16* tb = sm + yi * ROWH + xi;

  // wave-uniform interior test (all lanes weight 2 for all 60 shifts)
  const int wx_lo = cbase + xhalf * 32;
  const int wy_lo = rbase - 5 + ywave * 8;
  const bool fastw = (wx_lo >= 5) && (wx_lo + 31 <= 240) &&
                     (wy_lo >= 0) && (wy_lo + 7 <= 240);

  // i = 0 window; centers = halves (5,6) and (7,8)
  LOADROW(tb)
  #pragma unroll
  for (int pl = 0; pl < 6; ++pl) {
    cenA[pl] = exth<5>(wd[pl]);
    cenB[pl] = exth<7>(wd[pl]);
  }

  float tot;
  if (fastw) {
    SHF(6) SHF(7) SHF(8) SHF(9) SHF(10)          // i=0: j=1..5
    #pragma unroll 1
    for (int ii = 1; ii <= 5; ++ii) {
      tb += ROWH;
      LOADROW(tb)
      ROWF
    }
    tot = 2.0f * ((float)accA.x + (float)accA.y + (float)accB.x + (float)accB.y);
  } else {
    // target-x validity per window half m: x = xp0 + m - 5
    unsigned xk[7];
    #pragma unroll
    for (int m = 0; m < 7; ++m) {
      h2 xx;
      xx.x = ((unsigned)(xp0 + 2 * m - 5) < 246u) ? (half_t)1.0f : (half_t)0.0f;
      xx.y = ((unsigned)(xp0 + 2 * m - 4) < 246u) ? (half_t)1.0f : (half_t)0.0f;
      xk[m] = U32(xx);
    }
    const half_t ymh = ((unsigned)y < 246u) ? (half_t)1.0f : (half_t)0.0f;
    h2 ym2; ym2.x = ymh; ym2.y = ymh;
    const h2 cenfA = ym2 * exth<5>(xk);   // center validity for p=0,1
    const h2 cenfB = ym2 * exth<7>(xk);   // p=2,3

    h2 yok2; yok2.x = ymh; yok2.y = ymh;  // i=0: target row == center row
    SHM(6) SHM(7) SHM(8) SHM(9) SHM(10)
    #pragma unroll 1
    for (int ii = 1; ii <= 5; ++ii) {
      tb += ROWH;
      LOADROW(tb)
      const half_t yv = ((unsigned)(y + ii) < 246u) ? (half_t)1.0f : (half_t)0.0f;
      yok2.x = yv; yok2.y = yv;
      ROWM
    }
    tot = (float)accA.x + (float)accA.y + (float)accB.x + (float)accB.y;
  }

  // ---- reduce: wave shuffle -> LDS -> one atomic per block ----
  #pragma unroll
  for (int off = 32; off > 0; off >>= 1)
    tot += __shfl_down(tot, off, 64);
  if (lane == 0) wsum[wave] = tot;
  __syncthreads();
  if (tid == 0) {
    const float scale = 1.0f / 116190720.0f;   // 16*246*246*120
    atomicAdd(out, (wsum[0] + wsum[1] + wsum[2] + wsum[3]) * scale);
  }
}

extern "C" void kernel_launch(void* const* d_in, const int* in_sizes, int n_in,
                              void* d_out, int out_size, void* d_ws, size_t ws_size,
                              hipStream_t stream) {
  (void)in_sizes; (void)n_in; (void)d_ws; (void)ws_size; (void)out_size;
  const float* orig = (const float*)d_in[0];
  const float* sim  = (const float*)d_in[1];
  float* out = (float*)d_out;

  hipMemsetAsync(out, 0, sizeof(float), stream);

  dim3 grid(4, 16, BATCH);   // 1024 blocks
  dim3 block(256);
  hipLaunchKernelGGL(contrast_loss_kernel, grid, block, 0, stream, orig, sim, out);
}